// Round 3
// baseline (28.420 us; speedup 1.0000x reference)
//
#include <hip/hip_runtime.h>
#include <math.h>

#define K_SIZE 11
#define HALF 5
#define BLOCK 256
#define EPT 8            // outputs per thread
#define TILE (BLOCK*EPT) // 2048 outputs per block-tile
#define GRID 2048        // grid-stride: ~4 tiles per block at N=2^24

typedef float floatx4 __attribute__((ext_vector_type(4)));

__global__ __launch_bounds__(BLOCK) void dilation1d_kernel(
    const float* __restrict__ in, const float* __restrict__ scale_p,
    float* __restrict__ out, int N)
{
    const float inv4s = 1.0f / (4.0f * scale_p[0]);
    // h[d] = -(d^2)/(4*scale); symmetric, h[0] == -0.0 (exact no-op add)
    float h[HALF + 1];
    #pragma unroll
    for (int d = 0; d <= HALF; ++d) h[d] = -(float)(d * d) * inv4s;

    const int ntiles = (N + TILE - 1) / TILE;
    for (int tile = blockIdx.x; tile < ntiles; tile += gridDim.x) {
        const int base  = tile * TILE + threadIdx.x * EPT; // first output index
        const int lbase = base - 8;                        // first loaded idx (16B aligned)
        const bool interior = (tile != 0) && (tile != ntiles - 1);

        // r[j] = in[base - 8 + j], j = 0..23 ; window needed: j = u+8-5 .. u+8+5
        float r[24];
        if (interior) {
            const floatx4* p = (const floatx4*)(in + lbase);
            #pragma unroll
            for (int v = 0; v < 6; ++v) {
                floatx4 f = p[v];
                r[v*4+0] = f.x; r[v*4+1] = f.y; r[v*4+2] = f.z; r[v*4+3] = f.w;
            }
        } else {
            #pragma unroll
            for (int j = 0; j < 24; ++j) {
                int idx = lbase + j;
                r[j] = (idx >= 0 && idx < N) ? in[idx] : -INFINITY;
            }
        }

        // out[base+u] = max_d ( max(x[i-d], x[i+d]) + h[d] ), center tap free.
        // Bit-exact vs reference: RN is monotone, so max(a,b)+h == max(a+h,b+h).
        float o[EPT];
        #pragma unroll
        for (int u = 0; u < EPT; ++u) {
            float m = r[u + 8]; // h[0] adds -0.0 -> identity
            #pragma unroll
            for (int d = 1; d <= HALF; ++d)
                m = fmaxf(m, fmaxf(r[u + 8 - d], r[u + 8 + d]) + h[d]);
            o[u] = m;
        }

        if (interior || base + EPT <= N) {
            floatx4* po = (floatx4*)(out + base);
            floatx4 v0 = {o[0], o[1], o[2], o[3]};
            floatx4 v1 = {o[4], o[5], o[6], o[7]};
            __builtin_nontemporal_store(v0, po);
            __builtin_nontemporal_store(v1, po + 1);
        } else {
            #pragma unroll
            for (int u = 0; u < EPT; ++u)
                if (base + u < N) out[base + u] = o[u];
        }
    }
}

extern "C" void kernel_launch(void* const* d_in, const int* in_sizes, int n_in,
                              void* d_out, int out_size, void* d_ws, size_t ws_size,
                              hipStream_t stream) {
    const float* in      = (const float*)d_in[0];
    const float* scale_p = (const float*)d_in[1];
    float* out           = (float*)d_out;
    const int N = in_sizes[0];
    const int ntiles = (N + TILE - 1) / TILE;
    const int grid = ntiles < GRID ? ntiles : GRID;
    hipLaunchKernelGGL(dilation1d_kernel, dim3(grid), dim3(BLOCK), 0, stream,
                       in, scale_p, out, N);
}